// Round 3
// baseline (1266.686 us; speedup 1.0000x reference)
//
#include <hip/hip_runtime.h>
#include <cstdint>

// LWMCrossAttention fused kernel for MI355X (gfx950) — v3.
// Superwindow blocks: one block = 16x32 pixels (two adjacent 16x16 windows), so
// every HBM read and write is a full 128 B line — kills the partial-line RMW
// amplification v2 exposed (WRITE_SIZE 4.4x ideal). Identity block mapping
// (no XCD swizzle; blocks are line-self-sufficient). 32 KB LDS chunks
// (4 rows x 32 px x 128 ch bf16), 4 blocks/CU, float4 staging loads.

typedef short V8AB __attribute__((ext_vector_type(8)));
typedef float V4F  __attribute__((ext_vector_type(4)));

#define IMG_W   256
#define HWSZ    65536       // 256*256
#define CCH     128
#define EPSF    1e-6f

__device__ __forceinline__ unsigned short f2bits(float f) {
    return __builtin_bit_cast(unsigned short, (__bf16)f);   // RNE
}

// W-operand fragment: frag[m=lane&15 -> weight row][k=(lane>>4)*8+j -> 8 cols].
__device__ __forceinline__ V8AB load_wfrag(const float* __restrict__ wrow) {
    float4 w0 = *(const float4*)(wrow);
    float4 w1 = *(const float4*)(wrow + 4);
    V8AB r;
    r[0] = (short)f2bits(w0.x); r[1] = (short)f2bits(w0.y);
    r[2] = (short)f2bits(w0.z); r[3] = (short)f2bits(w0.w);
    r[4] = (short)f2bits(w1.x); r[5] = (short)f2bits(w1.y);
    r[6] = (short)f2bits(w1.z); r[7] = (short)f2bits(w1.w);
    return r;
}

// Stage one chunk: 4 image rows x 32 px x 128 ch (fp32 -> bf16, 32 KB).
// Local token t = r*32+pix; MFMA tile = (pix>>4)*4 + r  (tiles 0..3 win A,
// 4..7 win B), m = pix&15. Chunk#(tile,ks,lane) = tile*256 + ks*64 + lane is
// lane-linear for the A-fragment read. Reads: full 128 B line per (ch,row).
__device__ __forceinline__ void stage_chunk(const float* __restrict__ src,
                                            short* xbuf, int tid, int pixoff) {
    #pragma unroll
    for (int it = 0; it < 2; ++it) {
        int p   = it * 256 + tid;      // 0..511
        int q4  = p & 31;              // token-quad id
        int cg  = p >> 5;              // channel group 0..15 (8 ch each)
        int t0  = q4 * 4;              // local token 0..124
        int r   = t0 >> 5;             // row-in-chunk 0..3
        int pix = t0 & 31;             // 0,4,...,28
        int tile = ((pix >> 4) << 2) | r;
        int m    = pix & 15;           // 0,4,8,12
        int ca   = (tile << 8) | ((cg >> 2) << 6) | ((cg & 3) << 4) | m;
        const float* g = src + (size_t)(cg * 8) * HWSZ + pixoff + r * IMG_W + pix;
        float4 f[8];
        #pragma unroll
        for (int j = 0; j < 8; ++j)
            f[j] = *(const float4*)(g + (size_t)j * HWSZ);
        #pragma unroll
        for (int t = 0; t < 4; ++t) {
            V8AB v;
            #pragma unroll
            for (int j = 0; j < 8; ++j) {
                float e = (t == 0) ? f[j].x : (t == 1) ? f[j].y : (t == 2) ? f[j].z : f[j].w;
                v[j] = (short)f2bits(e);
            }
            *(V8AB*)(xbuf + (size_t)(ca + t) * 8) = v;
        }
    }
}

__global__ __launch_bounds__(256, 4)
void lwm_fused_kernel(const float* __restrict__ x1, const float* __restrict__ x2,
                      const float* __restrict__ Wq, const float* __restrict__ Wkv,
                      float* __restrict__ out) {
    __shared__ __align__(16) short xbuf[16384];   // 32 KB

    const int tid  = threadIdx.x;
    const int lane = tid & 63;
    const int wv   = tid >> 6;        // wave 0..3, owns heads wv and wv+4
    const int l15  = lane & 15;
    const int quad = lane >> 4;
    const int zhi  = quad >> 1;       // 1 for quads 2,3 (zero K-half of K=32 mfmas)

    // 1024 blocks: b (8) x wy (16) x wx (8 superwindows of 32 px)
    const int bid = blockIdx.x;
    const int b   = bid >> 7;
    const int wy  = (bid >> 3) & 15;
    const int wx  = bid & 7;
    const int base = wy * 16 * IMG_W + wx * 32;

    const float* x1b  = x1 + (size_t)b * CCH * HWSZ;
    const float* x2b  = x2 + (size_t)b * CCH * HWSZ;
    float*       outb = out + (size_t)b * CCH * HWSZ;

    // ================= Phase A: x2 -> k,v ; accumulate per [hh][win] ==========
    float ksum[2][2] = {{0.f,0.f},{0.f,0.f}};
    float vsum[2][2] = {{0.f,0.f},{0.f,0.f}};
    V4F kvacc[2][2] = {{{0.f,0.f,0.f,0.f},{0.f,0.f,0.f,0.f}},
                       {{0.f,0.f,0.f,0.f},{0.f,0.f,0.f,0.f}}};

    #pragma unroll
    for (int chunk = 0; chunk < 4; ++chunk) {
        stage_chunk(x2b, xbuf, tid, base + chunk * 4 * IMG_W);
        __syncthreads();
        #pragma unroll
        for (int hh = 0; hh < 2; ++hh) {
            const int head = wv + 4 * hh;
            V8AB bk[4], bv[4];
            #pragma unroll
            for (int ks = 0; ks < 4; ++ks) {
                bk[ks] = load_wfrag(Wkv + (size_t)(head * 16 + l15) * CCH + ks * 32 + quad * 8);
                bv[ks] = load_wfrag(Wkv + (size_t)(CCH + head * 16 + l15) * CCH + ks * 32 + quad * 8);
            }
            #pragma unroll
            for (int win = 0; win < 2; ++win) {
                #pragma unroll
                for (int s2 = 0; s2 < 2; ++s2) {     // 32 tokens (2 tiles)
                    const int tA = win * 4 + 2 * s2;
                    V4F aK0 = {0,0,0,0}, aK1 = {0,0,0,0}, aV0 = {0,0,0,0}, aV1 = {0,0,0,0};
                    #pragma unroll
                    for (int ks = 0; ks < 4; ++ks) {
                        V8AB a0 = *(const V8AB*)(xbuf + (size_t)((tA    ) * 256 + ks * 64 + lane) * 8);
                        V8AB a1 = *(const V8AB*)(xbuf + (size_t)((tA + 1) * 256 + ks * 64 + lane) * 8);
                        aK0 = __builtin_amdgcn_mfma_f32_16x16x32_bf16(a0, bk[ks], aK0, 0, 0, 0);
                        aV0 = __builtin_amdgcn_mfma_f32_16x16x32_bf16(a0, bv[ks], aV0, 0, 0, 0);
                        aK1 = __builtin_amdgcn_mfma_f32_16x16x32_bf16(a1, bk[ks], aK1, 0, 0, 0);
                        aV1 = __builtin_amdgcn_mfma_f32_16x16x32_bf16(a1, bv[ks], aV1, 0, 0, 0);
                    }
                    // token-major D: [tok=quad*4+r][ch=l15]; normalize k, pack early.
                    unsigned pk0[2], pk1[2], pv0[2], pv1[2];
                    #pragma unroll
                    for (int r = 0; r < 4; ++r) {
                        float s = aK0[r] * aK0[r];
                        s += __shfl_xor(s, 1); s += __shfl_xor(s, 2);
                        s += __shfl_xor(s, 4); s += __shfl_xor(s, 8);
                        float kn0 = aK0[r] * rsqrtf(s);
                        float t = aK1[r] * aK1[r];
                        t += __shfl_xor(t, 1); t += __shfl_xor(t, 2);
                        t += __shfl_xor(t, 4); t += __shfl_xor(t, 8);
                        float kn1 = aK1[r] * rsqrtf(t);
                        ksum[hh][win] += kn0 + kn1;
                        vsum[hh][win] += aV0[r] + aV1[r];
                        unsigned uk0 = f2bits(kn0),     uk1 = f2bits(kn1);
                        unsigned uv0 = f2bits(aV0[r]),  uv1 = f2bits(aV1[r]);
                        if ((r & 1) == 0) {
                            pk0[r >> 1] = uk0;  pk1[r >> 1] = uk1;
                            pv0[r >> 1] = uv0;  pv1[r >> 1] = uv1;
                        } else {
                            pk0[r >> 1] |= uk0 << 16;  pk1[r >> 1] |= uk1 << 16;
                            pv0[r >> 1] |= uv0 << 16;  pv1[r >> 1] |= uv1 << 16;
                        }
                    }
                    // kv_acc operands: A[m=ck=l15][k=tok], B[k=tok][n=cv=l15]
                    V8AB ka, vb;
                    #pragma unroll
                    for (int j = 0; j < 8; ++j) {
                        int src = l15 + ((((quad & 1) * 2) + (j >> 2)) << 4);
                        unsigned k0 = __shfl(pk0[(j >> 1) & 1], src);
                        unsigned k1 = __shfl(pk1[(j >> 1) & 1], src);
                        unsigned v0 = __shfl(pv0[(j >> 1) & 1], src);
                        unsigned v1 = __shfl(pv1[(j >> 1) & 1], src);
                        unsigned ku = zhi ? k1 : k0;
                        unsigned vu = zhi ? v1 : v0;
                        ka[j] = (short)((j & 1) ? (ku >> 16) : (ku & 0xffffu));
                        vb[j] = (short)((j & 1) ? (vu >> 16) : (vu & 0xffffu));
                    }
                    kvacc[hh][win] = __builtin_amdgcn_mfma_f32_16x16x32_bf16(ka, vb, kvacc[hh][win], 0, 0, 0);
                }
            }
        }
        __syncthreads();
    }

    // ================= finalize per [hh][win]: kvb, vs, ksf4 ==================
    V8AB  kvb[2][2];
    float ksf4[2][2][4];
    float vs[2][2];
    #pragma unroll
    for (int hh = 0; hh < 2; ++hh) {
        #pragma unroll
        for (int win = 0; win < 2; ++win) {
            float ks_ = ksum[hh][win];
            ks_ += __shfl_xor(ks_, 16); ks_ += __shfl_xor(ks_, 32);
            float vs_ = vsum[hh][win];
            vs_ += __shfl_xor(vs_, 16); vs_ += __shfl_xor(vs_, 32);
            vs[hh][win] = vs_;
            const float ksf = ks_ + EPSF;            // per-channel (ch = l15)
            // kvacc D[ck=quad*4+r][cv=l15] -> attn B-frag [k=ck][n=cv], hi rows zero
            #pragma unroll
            for (int j = 0; j < 8; ++j) {
                int src = l15 + ((((quad & 1) * 2) + (j >> 2)) << 4);
                float kv = __shfl(kvacc[hh][win][j & 3], src);
                kvb[hh][win][j] = zhi ? (short)0 : (short)f2bits(kv);
            }
            #pragma unroll
            for (int r = 0; r < 4; ++r)
                ksf4[hh][win][r] = __shfl(ksf, quad * 4 + r);
        }
    }

    // ================= Phase B: x1 -> q (swapped mfma) ; attn ; store =========
    #pragma unroll
    for (int chunk = 0; chunk < 4; ++chunk) {
        stage_chunk(x1b, xbuf, tid, base + chunk * 4 * IMG_W);
        __syncthreads();
        #pragma unroll
        for (int hh = 0; hh < 2; ++hh) {
            const int head = wv + 4 * hh;
            V8AB bq[4];
            #pragma unroll
            for (int ks = 0; ks < 4; ++ks)
                bq[ks] = load_wfrag(Wq + (size_t)(head * 16 + l15) * CCH + ks * 32 + quad * 8);
            #pragma unroll
            for (int rr = 0; rr < 4; ++rr) {
                #pragma unroll
                for (int win = 0; win < 2; ++win) {   // win inner: line halves back-to-back
                    const int tile = win * 4 + rr;
                    // swapped: A=W, B=x  ->  D[ch=quad*4+r][tok=l15]
                    V4F acc = {0,0,0,0};
                    #pragma unroll
                    for (int ks = 0; ks < 4; ++ks) {
                        V8AB a = *(const V8AB*)(xbuf + (size_t)(tile * 256 + ks * 64 + lane) * 8);
                        acc = __builtin_amdgcn_mfma_f32_16x16x32_bf16(bq[ks], a, acc, 0, 0, 0);
                    }
                    // per-token norm over 16 ch: 4 in-lane + cross-quad
                    float s = acc[0]*acc[0] + acc[1]*acc[1] + acc[2]*acc[2] + acc[3]*acc[3];
                    s += __shfl_xor(s, 16); s += __shfl_xor(s, 32);
                    const float rn = rsqrtf(s);
                    const float qn0 = acc[0]*rn, qn1 = acc[1]*rn, qn2 = acc[2]*rn, qn3 = acc[3]*rn;
                    // tailor dot: pd(tok=l15) = sum_ch qn*ksf
                    float pd = qn0*ksf4[hh][win][0] + qn1*ksf4[hh][win][1]
                             + qn2*ksf4[hh][win][2] + qn3*ksf4[hh][win][3];
                    pd += __shfl_xor(pd, 16); pd += __shfl_xor(pd, 32);
                    const float ta = 1.0f / (256.0f + pd);
                    // qa A-frag [m=tok=l15][k=ch=quad*8+j] via packed shuffles
                    const unsigned pq0 = (unsigned)f2bits(qn0) | ((unsigned)f2bits(qn1) << 16);
                    const unsigned pq1 = (unsigned)f2bits(qn2) | ((unsigned)f2bits(qn3) << 16);
                    V8AB qa;
                    #pragma unroll
                    for (int j = 0; j < 8; ++j) {
                        int src = l15 + ((((quad & 1) * 2) + (j >> 2)) << 4);
                        unsigned u  = __shfl(((j >> 1) & 1) ? pq1 : pq0, src);
                        unsigned hs = (j & 1) ? (u >> 16) : (u & 0xffffu);
                        qa[j] = zhi ? (short)0 : (short)hs;
                    }
                    V4F z = {0,0,0,0};
                    V4F d = __builtin_amdgcn_mfma_f32_16x16x32_bf16(qa, kvb[hh][win], z, 0, 0, 0);
                    // D[tok=quad*4+r][ch=l15]; one float4 store per lane
                    float4 o;
                    o.x = (d[0] + vs[hh][win]) * __shfl(ta, quad * 4 + 0);
                    o.y = (d[1] + vs[hh][win]) * __shfl(ta, quad * 4 + 1);
                    o.z = (d[2] + vs[hh][win]) * __shfl(ta, quad * 4 + 2);
                    o.w = (d[3] + vs[hh][win]) * __shfl(ta, quad * 4 + 3);
                    *(float4*)(outb + (size_t)(head * 16 + l15) * HWSZ + base
                               + (chunk * 4 + rr) * IMG_W + win * 16 + quad * 4) = o;
                }
            }
        }
        if (chunk < 3) __syncthreads();
    }
}

extern "C" void kernel_launch(void* const* d_in, const int* in_sizes, int n_in,
                              void* d_out, int out_size, void* d_ws, size_t ws_size,
                              hipStream_t stream) {
    const float* x1  = (const float*)d_in[0];
    const float* x2  = (const float*)d_in[1];
    const float* Wq  = (const float*)d_in[2];
    const float* Wkv = (const float*)d_in[3];
    float* out = (float*)d_out;
    lwm_fused_kernel<<<dim3(1024), dim3(256), 0, stream>>>(x1, x2, Wq, Wkv, out);
}

// Round 6
// 747.297 us; speedup vs baseline: 1.6950x; 1.6950x over previous
//
#include <hip/hip_runtime.h>
#include <cstdint>

// LWMCrossAttention fused kernel for MI355X (gfx950) — v4 (2nd resubmit;
// rounds 4 and 5 both failed on GPU acquisition, no counters produced).
// v3 superwindow structure (block = 16x32 px = 2 windows, full-128B-line I/O)
// with the v2/v3 scratch-spill regression fixed: __launch_bounds__(256,2).
// v2/v3 reported VGPR_Count=64 with ~110-130 live values -> compiler spilled
// to scratch, producing ~1 GB of phantom HBM write traffic (WRITE_SIZE 5.2x
// ideal) and 8% VALUBusy. (256,2) caps VGPR at 256; expected allocation ~128
// (v1 evidence) -> still 4 blocks/CU with 32 KB LDS, no spill.
// Chunk loops rolled (#pragma unroll 1) to keep peak register pressure down.

typedef short V8AB __attribute__((ext_vector_type(8)));
typedef float V4F  __attribute__((ext_vector_type(4)));

#define IMG_W   256
#define HWSZ    65536       // 256*256
#define CCH     128
#define EPSF    1e-6f

__device__ __forceinline__ unsigned short f2bits(float f) {
    return __builtin_bit_cast(unsigned short, (__bf16)f);   // RNE
}

// W-operand fragment: frag[m=lane&15 -> weight row][k=(lane>>4)*8+j -> 8 cols].
__device__ __forceinline__ V8AB load_wfrag(const float* __restrict__ wrow) {
    float4 w0 = *(const float4*)(wrow);
    float4 w1 = *(const float4*)(wrow + 4);
    V8AB r;
    r[0] = (short)f2bits(w0.x); r[1] = (short)f2bits(w0.y);
    r[2] = (short)f2bits(w0.z); r[3] = (short)f2bits(w0.w);
    r[4] = (short)f2bits(w1.x); r[5] = (short)f2bits(w1.y);
    r[6] = (short)f2bits(w1.z); r[7] = (short)f2bits(w1.w);
    return r;
}

// Stage one chunk: 4 image rows x 32 px x 128 ch (fp32 -> bf16, 32 KB).
// Local token t = r*32+pix; MFMA tile = (pix>>4)*4 + r  (tiles 0..3 win A,
// 4..7 win B), m = pix&15. Chunk#(tile,ks,lane) = tile*256 + ks*64 + lane is
// lane-linear for the A-fragment read. Reads: full 128 B line per (ch,row).
__device__ __forceinline__ void stage_chunk(const float* __restrict__ src,
                                            short* xbuf, int tid, int pixoff) {
    #pragma unroll
    for (int it = 0; it < 2; ++it) {
        int p   = it * 256 + tid;      // 0..511
        int q4  = p & 31;              // token-quad id
        int cg  = p >> 5;              // channel group 0..15 (8 ch each)
        int t0  = q4 * 4;              // local token 0..124
        int r   = t0 >> 5;             // row-in-chunk 0..3
        int pix = t0 & 31;             // 0,4,...,28
        int tile = ((pix >> 4) << 2) | r;
        int m    = pix & 15;           // 0,4,8,12
        int ca   = (tile << 8) | ((cg >> 2) << 6) | ((cg & 3) << 4) | m;
        const float* g = src + (size_t)(cg * 8) * HWSZ + pixoff + r * IMG_W + pix;
        float4 f[8];
        #pragma unroll
        for (int j = 0; j < 8; ++j)
            f[j] = *(const float4*)(g + (size_t)j * HWSZ);
        #pragma unroll
        for (int t = 0; t < 4; ++t) {
            V8AB v;
            #pragma unroll
            for (int j = 0; j < 8; ++j) {
                float e = (t == 0) ? f[j].x : (t == 1) ? f[j].y : (t == 2) ? f[j].z : f[j].w;
                v[j] = (short)f2bits(e);
            }
            *(V8AB*)(xbuf + (size_t)(ca + t) * 8) = v;
        }
    }
}

__global__ __launch_bounds__(256, 2)
void lwm_fused_kernel(const float* __restrict__ x1, const float* __restrict__ x2,
                      const float* __restrict__ Wq, const float* __restrict__ Wkv,
                      float* __restrict__ out) {
    __shared__ __align__(16) short xbuf[16384];   // 32 KB

    const int tid  = threadIdx.x;
    const int lane = tid & 63;
    const int wv   = tid >> 6;        // wave 0..3, owns heads wv and wv+4
    const int l15  = lane & 15;
    const int quad = lane >> 4;
    const int zhi  = quad >> 1;       // 1 for quads 2,3 (zero K-half of K=32 mfmas)

    // 1024 blocks: b (8) x wy (16) x wx (8 superwindows of 32 px)
    const int bid = blockIdx.x;
    const int b   = bid >> 7;
    const int wy  = (bid >> 3) & 15;
    const int wx  = bid & 7;
    const int base = wy * 16 * IMG_W + wx * 32;

    const float* x1b  = x1 + (size_t)b * CCH * HWSZ;
    const float* x2b  = x2 + (size_t)b * CCH * HWSZ;
    float*       outb = out + (size_t)b * CCH * HWSZ;

    // ================= Phase A: x2 -> k,v ; accumulate per [hh][win] ==========
    float ksum[2][2] = {{0.f,0.f},{0.f,0.f}};
    float vsum[2][2] = {{0.f,0.f},{0.f,0.f}};
    V4F kvacc[2][2] = {{{0.f,0.f,0.f,0.f},{0.f,0.f,0.f,0.f}},
                       {{0.f,0.f,0.f,0.f},{0.f,0.f,0.f,0.f}}};

    #pragma unroll 1
    for (int chunk = 0; chunk < 4; ++chunk) {
        stage_chunk(x2b, xbuf, tid, base + chunk * 4 * IMG_W);
        __syncthreads();
        #pragma unroll
        for (int hh = 0; hh < 2; ++hh) {
            const int head = wv + 4 * hh;
            V8AB bk[4], bv[4];
            #pragma unroll
            for (int ks = 0; ks < 4; ++ks) {
                bk[ks] = load_wfrag(Wkv + (size_t)(head * 16 + l15) * CCH + ks * 32 + quad * 8);
                bv[ks] = load_wfrag(Wkv + (size_t)(CCH + head * 16 + l15) * CCH + ks * 32 + quad * 8);
            }
            #pragma unroll
            for (int win = 0; win < 2; ++win) {
                #pragma unroll
                for (int s2 = 0; s2 < 2; ++s2) {     // 32 tokens (2 tiles)
                    const int tA = win * 4 + 2 * s2;
                    V4F aK0 = {0,0,0,0}, aK1 = {0,0,0,0}, aV0 = {0,0,0,0}, aV1 = {0,0,0,0};
                    #pragma unroll
                    for (int ks = 0; ks < 4; ++ks) {
                        V8AB a0 = *(const V8AB*)(xbuf + (size_t)((tA    ) * 256 + ks * 64 + lane) * 8);
                        V8AB a1 = *(const V8AB*)(xbuf + (size_t)((tA + 1) * 256 + ks * 64 + lane) * 8);
                        aK0 = __builtin_amdgcn_mfma_f32_16x16x32_bf16(a0, bk[ks], aK0, 0, 0, 0);
                        aV0 = __builtin_amdgcn_mfma_f32_16x16x32_bf16(a0, bv[ks], aV0, 0, 0, 0);
                        aK1 = __builtin_amdgcn_mfma_f32_16x16x32_bf16(a1, bk[ks], aK1, 0, 0, 0);
                        aV1 = __builtin_amdgcn_mfma_f32_16x16x32_bf16(a1, bv[ks], aV1, 0, 0, 0);
                    }
                    // token-major D: [tok=quad*4+r][ch=l15]; normalize k, pack early.
                    unsigned pk0[2], pk1[2], pv0[2], pv1[2];
                    #pragma unroll
                    for (int r = 0; r < 4; ++r) {
                        float s = aK0[r] * aK0[r];
                        s += __shfl_xor(s, 1); s += __shfl_xor(s, 2);
                        s += __shfl_xor(s, 4); s += __shfl_xor(s, 8);
                        float kn0 = aK0[r] * rsqrtf(s);
                        float t = aK1[r] * aK1[r];
                        t += __shfl_xor(t, 1); t += __shfl_xor(t, 2);
                        t += __shfl_xor(t, 4); t += __shfl_xor(t, 8);
                        float kn1 = aK1[r] * rsqrtf(t);
                        ksum[hh][win] += kn0 + kn1;
                        vsum[hh][win] += aV0[r] + aV1[r];
                        unsigned uk0 = f2bits(kn0),     uk1 = f2bits(kn1);
                        unsigned uv0 = f2bits(aV0[r]),  uv1 = f2bits(aV1[r]);
                        if ((r & 1) == 0) {
                            pk0[r >> 1] = uk0;  pk1[r >> 1] = uk1;
                            pv0[r >> 1] = uv0;  pv1[r >> 1] = uv1;
                        } else {
                            pk0[r >> 1] |= uk0 << 16;  pk1[r >> 1] |= uk1 << 16;
                            pv0[r >> 1] |= uv0 << 16;  pv1[r >> 1] |= uv1 << 16;
                        }
                    }
                    // kv_acc operands: A[m=ck=l15][k=tok], B[k=tok][n=cv=l15]
                    V8AB ka, vb;
                    #pragma unroll
                    for (int j = 0; j < 8; ++j) {
                        int src = l15 + ((((quad & 1) * 2) + (j >> 2)) << 4);
                        unsigned k0 = __shfl(pk0[(j >> 1) & 1], src);
                        unsigned k1 = __shfl(pk1[(j >> 1) & 1], src);
                        unsigned v0 = __shfl(pv0[(j >> 1) & 1], src);
                        unsigned v1 = __shfl(pv1[(j >> 1) & 1], src);
                        unsigned ku = zhi ? k1 : k0;
                        unsigned vu = zhi ? v1 : v0;
                        ka[j] = (short)((j & 1) ? (ku >> 16) : (ku & 0xffffu));
                        vb[j] = (short)((j & 1) ? (vu >> 16) : (vu & 0xffffu));
                    }
                    kvacc[hh][win] = __builtin_amdgcn_mfma_f32_16x16x32_bf16(ka, vb, kvacc[hh][win], 0, 0, 0);
                }
            }
        }
        __syncthreads();
    }

    // ================= finalize per [hh][win]: kvb, vs, ksf4 ==================
    V8AB  kvb[2][2];
    float ksf4[2][2][4];
    float vs[2][2];
    #pragma unroll
    for (int hh = 0; hh < 2; ++hh) {
        #pragma unroll
        for (int win = 0; win < 2; ++win) {
            float ks_ = ksum[hh][win];
            ks_ += __shfl_xor(ks_, 16); ks_ += __shfl_xor(ks_, 32);
            float vs_ = vsum[hh][win];
            vs_ += __shfl_xor(vs_, 16); vs_ += __shfl_xor(vs_, 32);
            vs[hh][win] = vs_;
            const float ksf = ks_ + EPSF;            // per-channel (ch = l15)
            // kvacc D[ck=quad*4+r][cv=l15] -> attn B-frag [k=ck][n=cv], hi rows zero
            #pragma unroll
            for (int j = 0; j < 8; ++j) {
                int src = l15 + ((((quad & 1) * 2) + (j >> 2)) << 4);
                float kv = __shfl(kvacc[hh][win][j & 3], src);
                kvb[hh][win][j] = zhi ? (short)0 : (short)f2bits(kv);
            }
            #pragma unroll
            for (int r = 0; r < 4; ++r)
                ksf4[hh][win][r] = __shfl(ksf, quad * 4 + r);
        }
    }

    // ================= Phase B: x1 -> q (swapped mfma) ; attn ; store =========
    #pragma unroll 1
    for (int chunk = 0; chunk < 4; ++chunk) {
        stage_chunk(x1b, xbuf, tid, base + chunk * 4 * IMG_W);
        __syncthreads();
        #pragma unroll
        for (int hh = 0; hh < 2; ++hh) {
            const int head = wv + 4 * hh;
            V8AB bq[4];
            #pragma unroll
            for (int ks = 0; ks < 4; ++ks)
                bq[ks] = load_wfrag(Wq + (size_t)(head * 16 + l15) * CCH + ks * 32 + quad * 8);
            #pragma unroll
            for (int rr = 0; rr < 4; ++rr) {
                #pragma unroll
                for (int win = 0; win < 2; ++win) {   // win inner: line halves back-to-back
                    const int tile = win * 4 + rr;
                    // swapped: A=W, B=x  ->  D[ch=quad*4+r][tok=l15]
                    V4F acc = {0,0,0,0};
                    #pragma unroll
                    for (int ks = 0; ks < 4; ++ks) {
                        V8AB a = *(const V8AB*)(xbuf + (size_t)(tile * 256 + ks * 64 + lane) * 8);
                        acc = __builtin_amdgcn_mfma_f32_16x16x32_bf16(bq[ks], a, acc, 0, 0, 0);
                    }
                    // per-token norm over 16 ch: 4 in-lane + cross-quad
                    float s = acc[0]*acc[0] + acc[1]*acc[1] + acc[2]*acc[2] + acc[3]*acc[3];
                    s += __shfl_xor(s, 16); s += __shfl_xor(s, 32);
                    const float rn = rsqrtf(s);
                    const float qn0 = acc[0]*rn, qn1 = acc[1]*rn, qn2 = acc[2]*rn, qn3 = acc[3]*rn;
                    // tailor dot: pd(tok=l15) = sum_ch qn*ksf
                    float pd = qn0*ksf4[hh][win][0] + qn1*ksf4[hh][win][1]
                             + qn2*ksf4[hh][win][2] + qn3*ksf4[hh][win][3];
                    pd += __shfl_xor(pd, 16); pd += __shfl_xor(pd, 32);
                    const float ta = 1.0f / (256.0f + pd);
                    // qa A-frag [m=tok=l15][k=ch=quad*8+j] via packed shuffles
                    const unsigned pq0 = (unsigned)f2bits(qn0) | ((unsigned)f2bits(qn1) << 16);
                    const unsigned pq1 = (unsigned)f2bits(qn2) | ((unsigned)f2bits(qn3) << 16);
                    V8AB qa;
                    #pragma unroll
                    for (int j = 0; j < 8; ++j) {
                        int src = l15 + ((((quad & 1) * 2) + (j >> 2)) << 4);
                        unsigned u  = __shfl(((j >> 1) & 1) ? pq1 : pq0, src);
                        unsigned hs = (j & 1) ? (u >> 16) : (u & 0xffffu);
                        qa[j] = zhi ? (short)0 : (short)hs;
                    }
                    V4F z = {0,0,0,0};
                    V4F d = __builtin_amdgcn_mfma_f32_16x16x32_bf16(qa, kvb[hh][win], z, 0, 0, 0);
                    // D[tok=quad*4+r][ch=l15]; one float4 store per lane
                    float4 o;
                    o.x = (d[0] + vs[hh][win]) * __shfl(ta, quad * 4 + 0);
                    o.y = (d[1] + vs[hh][win]) * __shfl(ta, quad * 4 + 1);
                    o.z = (d[2] + vs[hh][win]) * __shfl(ta, quad * 4 + 2);
                    o.w = (d[3] + vs[hh][win]) * __shfl(ta, quad * 4 + 3);
                    *(float4*)(outb + (size_t)(head * 16 + l15) * HWSZ + base
                               + (chunk * 4 + rr) * IMG_W + win * 16 + quad * 4) = o;
                }
            }
        }
        __syncthreads();
    }
}

extern "C" void kernel_launch(void* const* d_in, const int* in_sizes, int n_in,
                              void* d_out, int out_size, void* d_ws, size_t ws_size,
                              hipStream_t stream) {
    const float* x1  = (const float*)d_in[0];
    const float* x2  = (const float*)d_in[1];
    const float* Wq  = (const float*)d_in[2];
    const float* Wkv = (const float*)d_in[3];
    float* out = (float*)d_out;
    lwm_fused_kernel<<<dim3(1024), dim3(256), 0, stream>>>(x1, x2, Wq, Wkv, out);
}